// Round 16
// baseline (165.252 us; speedup 1.0000x reference)
//
#include <hip/hip_runtime.h>
#include <math.h>

#define BATCH  32
#define CH     3
#define H      512
#define W      512
#define KWIN   15
#define PAD    7
#define TH     8                  // output rows per wave (16 -> 8 for 2x TLP)
#define NRR    (TH + KWIN - 1)    // 22 input rows per wave
#define STRIP  112                // output cols per wave (frame = 128 cols)
#define NSTRIP 5                  // ceil(512/112)
#define NWAVES (BATCH * (H / TH) * NSTRIP)   // 10240
#define DEPTH  5                  // software-pipeline depth (rows of loads in flight)

static __device__ __forceinline__ float2 min2(float2 a, float2 b) {
    float2 r;
    r.x = fminf(a.x, b.x);
    r.y = fminf(a.y, b.y);
    return r;
}

// R12 structure (best verified) with TH=16 -> 8: doubles wave count to 10240
// (40/CU requested) to test whether inter-wave latency overlap (TLP) is the
// missing factor. R14 counters: no throughput resource saturated (VALU 10%,
// HBM 2.2 of 6.3 TB/s, L2 ~4 of 34 TB/s) while per-step timing matched
// exposed-latency/depth with no TLP contribution; occupancy avg 9.3 waves/CU.
// R15 crashed on a bad TH=8 index adaptation (stores at y0+12 -> OOB);
// this version's mapping is re-derived and bounds-checked:
//   v-rows 0..21; out r = min(v[r..r+14]), r=0..7.
//   Phase A (q=0..14): v-row 7+q; P[q]=min(v7..v7+q); out7 = P[14] @ y0+7.
//   Phase B (q=15..21): v-row 21-q = 6..0; U streams; out r = min(U, P[r+7]) @ y0+r.
// DO NOT: add __launch_bounds__ (R3/R5 pathologies), grow per-thread arrays
// past full-unroll constant indexing (R13: LDS lowering), split channel-min
// into its own pass (R11: +5-7 us).
__global__ void dcp_fusedA(const float* __restrict__ I, float* __restrict__ out) {
    const int wid = blockIdx.x * 4 + (threadIdx.x >> 6);
    const int L   = threadIdx.x & 63;
    const int s   = wid % NSTRIP;
    const int rb  = (wid / NSTRIP) % (H / TH);
    const int b   = wid / (NSTRIP * (H / TH));
    const int y0  = rb * TH;
    const int f   = s * STRIP - 8 + 2 * L;            // frame col (even)
    const int cl  = min(max(f, 0), W - 2);            // clamped, keeps 8B alignment
    const bool cv = (f >= 0) && (f < W);
    const bool st = (L >= 4) && (L <= 59) && (f < W); // lane stores output

    const float* base = I + (size_t)b * CH * H * W + cl;
    float* outb = out + (size_t)b * H * W;

    // flat step q -> v-row index: 7..21 (P-build), then 6..0 (U-stream)
    auto seqrow = [](int q) { return q < KWIN ? PAD + q : 21 - q; };

    auto loadrow = [&](int i, float2& A, float2& B, float2& C) {
        const int yc = min(max(y0 - PAD + i, 0), H - 1);
        const float* p = base + (size_t)yc * W;
        A = *(const float2*)(p);
        B = *(const float2*)(p + (size_t)H * W);
        C = *(const float2*)(p + (size_t)2 * H * W);
    };

    auto hcompute = [&](int i, float2 A, float2 B, float2 C) -> float2 {
        const int y = y0 - PAD + i;
        float2 d = min2(min2(A, B), C);
        const bool pad = (y < 0) || (y >= H) || !cv;
        d.x = pad ? INFINITY : d.x;                   // select, not branch
        d.y = pad ? INFINITY : d.y;
        const float pm = fminf(d.x, d.y);             // pair min (cols f,f+1)
        const float t2 = fminf(pm, __shfl_down(pm, 1));
        const float t4 = fminf(t2, __shfl_down(t2, 2));
        const float q7 = fminf(t4, __shfl_up(t4, 3)); // cols f-6..f+7
        float2 wv;
        wv.x = fminf(q7, __shfl_up(d.y, 4));          // + col f-7
        wv.y = fminf(q7, __shfl_down(d.x, 4));        // + col f+8
        return wv;
    };

    float2 Ab[DEPTH], Bb[DEPTH], Cb[DEPTH];
    #pragma unroll
    for (int j = 0; j < DEPTH; ++j)
        loadrow(seqrow(j), Ab[j], Bb[j], Cb[j]);      // 15 loads issued up front

    float2 P[KWIN];
    float2 U;
    #pragma unroll
    for (int q = 0; q < NRR; ++q) {
        const int sl = q % DEPTH;                     // constant-folded (unrolled)
        const float2 h = hcompute(seqrow(q), Ab[sl], Bb[sl], Cb[sl]);
        if (q + DEPTH < NRR)
            loadrow(seqrow(q + DEPTH), Ab[sl], Bb[sl], Cb[sl]);

        if (q < KWIN) {                               // Phase A: v-rows 7..21
            P[q] = (q == 0) ? h : min2(P[q - 1], h);  // P[q] = min(v7..v7+q)
            if (q == KWIN - 1 && st)                  // out7 = min(v7..v21) = P[14]
                *(float2*)(outb + (size_t)(y0 + PAD) * W + f) = P[KWIN - 1];
        } else {                                      // Phase B: v-rows 6..0
            const int r = 21 - q;                     // 6..0
            U = (q == KWIN) ? h : min2(U, h);         // U = min(v[r..6])
            if (st)                                   // out r = min(U, P[r+7])
                *(float2*)(outb + (size_t)(y0 + r) * W + f) = min2(U, P[r + PAD]);
        }
    }
}

extern "C" void kernel_launch(void* const* d_in, const int* in_sizes, int n_in,
                              void* d_out, int out_size, void* d_ws, size_t ws_size,
                              hipStream_t stream) {
    const float* I = (const float*)d_in[0];
    // d_in[1] is k == 15, hard-coded (KWIN/PAD)
    float* out = (float*)d_out;
    dcp_fusedA<<<dim3(NWAVES / 4), dim3(256), 0, stream>>>(I, out);
}

// Round 17
// 157.846 us; speedup vs baseline: 1.0469x; 1.0469x over previous
//
#include <hip/hip_runtime.h>
#include <math.h>

#define BATCH  32
#define CH     3
#define H      512
#define W      512
#define KWIN   15
#define PAD    7
#define TH     16                 // output rows per wave
#define NRR    (TH + KWIN - 1)    // 30 input rows per wave
#define STRIP  112                // output cols per wave (frame = 128 cols)
#define NSTRIP 5                  // ceil(512/112)
#define NWAVES (BATCH * (H / TH) * NSTRIP)   // 5120
#define DEPTH  5                  // software-pipeline depth (rows of loads in flight)

static __device__ __forceinline__ float2 min2(float2 a, float2 b) {
    float2 r;
    r.x = fminf(a.x, b.x);
    r.y = fminf(a.y, b.y);
    return r;
}

// FINAL (best verified: R12 159.9 us, R14 repro 161.1 us): fully fused
// dark-channel + 15x15 min-pool. Zero LDS, zero barriers. Wave = 16 out rows
// x 112 out cols; lane owns 2 frame cols. Depth-5 software pipeline keeps 15
// independent b64 loads (~7.5 KB/wave) in flight. Loads unconditional
// (clamped row; +inf by select after load). h-min via 5 shuffles/row;
// vertical 15-min via van Herk (P-array + streamed U).
//
// Measured ceiling evidence (R14/R16): VALU 10%, HBM 2.2/6.3 TB/s, L2 4/34
// TB/s — nothing saturated; yet MLP depth 2->5 gained 1.5% and TLP 2x (TH=8,
// 10240 waves) gained nothing. Six structures converge to 50-62 us kernel:
// per-CU memory-concurrency/latency ceiling for this windowed 3-stream read.
// DO NOT: add __launch_bounds__ (R3: 20-VGPR serialization; R5: 64-VGPR
// spill), grow per-thread arrays past full-unroll constant indexing (R13:
// lowered to 80 KB LDS), split channel-min into its own pass (R11: +5-7 us),
// TH=32 single-load van Herk (R13: unroll failure), TH=8 (R16: no gain).
__global__ void dcp_fused8(const float* __restrict__ I, float* __restrict__ out) {
    const int wid = blockIdx.x * 4 + (threadIdx.x >> 6);
    const int L   = threadIdx.x & 63;
    const int s   = wid % NSTRIP;
    const int rb  = (wid / NSTRIP) % (H / TH);
    const int b   = wid / (NSTRIP * (H / TH));
    const int y0  = rb * TH;
    const int f   = s * STRIP - 8 + 2 * L;            // frame col (even)
    const int cl  = min(max(f, 0), W - 2);            // clamped, keeps 8B alignment
    const bool cv = (f >= 0) && (f < W);
    const bool st = (L >= 4) && (L <= 59) && (f < W); // lane stores output

    const float* base = I + (size_t)b * CH * H * W + cl;
    float* outb = out + (size_t)b * H * W;

    // flat step q -> h-min row index: 15..29 (P-build), then 14..0 (U-stream)
    auto seqrow = [](int q) { return q < KWIN ? KWIN + q : 29 - q; };

    auto loadrow = [&](int i, float2& A, float2& B, float2& C) {
        const int yc = min(max(y0 - PAD + i, 0), H - 1);
        const float* p = base + (size_t)yc * W;
        A = *(const float2*)(p);
        B = *(const float2*)(p + (size_t)H * W);
        C = *(const float2*)(p + (size_t)2 * H * W);
    };

    auto hcompute = [&](int i, float2 A, float2 B, float2 C) -> float2 {
        const int y = y0 - PAD + i;
        float2 d = min2(min2(A, B), C);
        const bool pad = (y < 0) || (y >= H) || !cv;
        d.x = pad ? INFINITY : d.x;                   // select, not branch
        d.y = pad ? INFINITY : d.y;
        const float pm = fminf(d.x, d.y);             // pair min (cols f,f+1)
        const float t2 = fminf(pm, __shfl_down(pm, 1));
        const float t4 = fminf(t2, __shfl_down(t2, 2));
        const float q7 = fminf(t4, __shfl_up(t4, 3)); // cols f-6..f+7
        float2 wv;
        wv.x = fminf(q7, __shfl_up(d.y, 4));          // + col f-7
        wv.y = fminf(q7, __shfl_down(d.x, 4));        // + col f+8
        return wv;
    };

    float2 Ab[DEPTH], Bb[DEPTH], Cb[DEPTH];
    #pragma unroll
    for (int j = 0; j < DEPTH; ++j)
        loadrow(seqrow(j), Ab[j], Bb[j], Cb[j]);      // 15 loads issued up front

    float2 P[KWIN];
    float2 U;
    #pragma unroll
    for (int q = 0; q < NRR; ++q) {
        const int sl = q % DEPTH;                     // constant-folded (unrolled)
        const float2 h = hcompute(seqrow(q), Ab[sl], Bb[sl], Cb[sl]);
        if (q + DEPTH < NRR)
            loadrow(seqrow(q + DEPTH), Ab[sl], Bb[sl], Cb[sl]);

        if (q == 0) {
            P[0] = h;
        } else if (q < KWIN) {
            P[q] = min2(P[q - 1], h);                 // P[q] = min(rows 15..15+q)
            if (q == KWIN - 1 && st)
                *(float2*)(outb + (size_t)(y0 + 15) * W + f) = P[KWIN - 1];
        } else if (q == KWIN) {                       // row 14
            U = h;
            if (st) *(float2*)(outb + (size_t)(y0 + 14) * W + f) = min2(U, P[13]);
        } else if (q < NRR - 1) {                     // rows 13..1
            const int r = 29 - q;
            U = min2(U, h);
            if (st) *(float2*)(outb + (size_t)(y0 + r) * W + f) = min2(U, P[r - 1]);
        } else {                                      // row 0
            U = min2(U, h);
            if (st) *(float2*)(outb + (size_t)y0 * W + f) = U;
        }
    }
}

extern "C" void kernel_launch(void* const* d_in, const int* in_sizes, int n_in,
                              void* d_out, int out_size, void* d_ws, size_t ws_size,
                              hipStream_t stream) {
    const float* I = (const float*)d_in[0];
    // d_in[1] is k == 15, hard-coded (KWIN/PAD)
    float* out = (float*)d_out;
    dcp_fused8<<<dim3(NWAVES / 4), dim3(256), 0, stream>>>(I, out);
}